// Round 1
// baseline (116.416 us; speedup 1.0000x reference)
//
#include <hip/hip_runtime.h>
#include <math.h>

// Deepmd angular descriptor, f32 in / f32 out. B=8, N=4096, M=96, OUT_W=384.
//
// R16: same all-dense load shape as R15 (each wave-iteration owns 2 rows =
// 192 contiguous stream elements = 3/lane, full-wave dense loads), but:
//  * WPB 16 -> 8 (512 threads), __launch_bounds__(512, 4): LDS still caps
//    occupancy at 2 blocks/CU (16 waves/CU), but the VGPR budget per wave
//    goes 64 -> 128. R15's (1024,8) pledge forced a 64-VGPR fit, which
//    serialized the 9 stream loads per iteration (read side measured only
//    2.3 TB/s). 128 VGPRs lets a whole iteration's loads stay in flight.
//  * Each wave owns 8 rows = 4 iterations; explicit depth-1 software
//    pipeline: iteration k+1's neighbors/mask/offsets loads are issued
//    before iteration k's geometry/ballot/store work.
// Ballot-rank + register merge + one b128+b64 store per row unchanged.
// LDS = 64 KB float4 position table; single __syncthreads.
#define M_NB   96
#define OUT_W  384
#define NATOM  4096
#define WPB    8
#define ITERS  4                      // 2 rows per iteration -> 8 rows/wave
#define LOWM   0x00000000FFFFFFFFull
#define HIGHM  0xFFFFFFFF00000000ull

// fold one item (row floats [base,base+3)) into this lane's output slots:
// float4 owns [4*lane,4*lane+4), float2 owns [256+2*lane,256+2*lane+2)
__device__ __forceinline__ void merge3(float4& a4, float2& a2, int base,
                                       float v0, float v1, float v2, int lane)
{
    const int f4lo = 4 * lane;
    const int f2lo = 256 + 2 * lane;
    const float v[3] = {v0, v1, v2};
    #pragma unroll
    for (int t = 0; t < 3; ++t) {
        const int idx = base + t;
        if      (idx == f4lo)     a4.x = v[t];
        else if (idx == f4lo + 1) a4.y = v[t];
        else if (idx == f4lo + 2) a4.z = v[t];
        else if (idx == f4lo + 3) a4.w = v[t];
        else if (idx == f2lo)     a2.x = v[t];
        else if (idx == f2lo + 1) a2.y = v[t];
    }
}

__global__ __launch_bounds__(64 * WPB, 4) void deepmd_angular_kernel(
    const float* __restrict__ positions,  // [B,N,3]
    const float* __restrict__ cell,       // [B,3,3]
    const float* __restrict__ offsets,    // [B,N,M,3]
    const float* __restrict__ mask,       // [B,N,M]
    const int*   __restrict__ neighbors,  // [B,N,M]
    float*       __restrict__ out,        // [B,N,OUT_W]
    int N)
{
    __shared__ float4 pos4_s[NATOM];        // 64 KB padded position table

    const int tid  = threadIdx.x;
    const int wv   = tid >> 6;
    const int lane = tid & 63;

    const int p0 = blockIdx.x * (WPB * 2 * ITERS);   // 64 rows per block
    const int b  = p0 / N;                           // uniform (64 | N)

    // ---- stage batch positions -> LDS (padded to 16 B/atom) ----
    {
        const float* pb_ = positions + (size_t)b * N * 3;
        for (int a = tid; a < NATOM; a += 64 * WPB) {
            const float3 v = *(const float3*)(pb_ + 3 * a);
            pos4_s[a] = make_float4(v.x, v.y, v.z, 0.f);
        }
    }
    __syncthreads();                             // only barrier in the kernel

    const float* cb = cell + (size_t)b * 9;      // uniform -> scalar loads
    const float c00 = cb[0], c01 = cb[1], c02 = cb[2];
    const float c10 = cb[3], c11 = cb[4], c12 = cb[5];
    const float c20 = cb[6], c21 = cb[7], c22 = cb[8];

    const int  r0    = p0 + wv * (2 * ITERS);    // wave's first row
    const long base0 = (long)r0 * M_NB;          // contiguous 8*96 elements

    // ---- prefetch iteration 0's stream loads ----
    int    pj0, pj1, pj2;
    float  pm0, pm1, pm2;
    float3 po0, po1, po2;
    {
        const long e0 = base0 + lane, e1 = e0 + 64, e2 = e0 + 128;
        pj0 = neighbors[e0]; pj1 = neighbors[e1]; pj2 = neighbors[e2];
        pm0 = mask[e0];      pm1 = mask[e1];      pm2 = mask[e2];
        po0 = *(const float3*)(offsets + e0 * 3);
        po1 = *(const float3*)(offsets + e1 * 3);
        po2 = *(const float3*)(offsets + e2 * 3);
    }

    #pragma unroll
    for (int it = 0; it < ITERS; ++it) {
        const int q0 = r0 + it * 2;              // first of this iter's 2 rows

        // consume prefetched regs
        const int    j0 = pj0, j1 = pj1, j2 = pj2;
        const float  m0 = pm0, m1 = pm1, m2 = pm2;
        const float3 o0 = po0, o1 = po1, o2 = po2;

        // ---- issue next iteration's loads (stay in flight under compute) ----
        if (it + 1 < ITERS) {
            const long e0 = base0 + (long)(it + 1) * 192 + lane;
            const long e1 = e0 + 64, e2 = e0 + 128;
            pj0 = neighbors[e0]; pj1 = neighbors[e1]; pj2 = neighbors[e2];
            pm0 = mask[e0];      pm1 = mask[e1];      pm2 = mask[e2];
            po0 = *(const float3*)(offsets + e0 * 3);
            po1 = *(const float3*)(offsets + e1 * 3);
            po2 = *(const float3*)(offsets + e2 * 3);
        }

        // ---- LDS gathers ----
        const int nn0 = q0 - b * N;
        const float4 pi0 = pos4_s[nn0];          // uniform broadcasts
        const float4 pi1 = pos4_s[nn0 + 1];
        const float4 pj0v = pos4_s[j0];
        const float4 pj1v = pos4_s[j1];
        const float4 pj2v = pos4_s[j2];
        const float4 pa  = (lane < 32) ? pi0 : pi1;   // item1's own atom

        // ---- cut per item (w = cut * dis_vec stored in-place) ----
        float w0x = pj0v.x - pi0.x + o0.x * c00 + o0.y * c10 + o0.z * c20;
        float w0y = pj0v.y - pi0.y + o0.x * c01 + o0.y * c11 + o0.z * c21;
        float w0z = pj0v.z - pi0.z + o0.x * c02 + o0.y * c12 + o0.z * c22;
        float d   = sqrtf(w0x * w0x + w0y * w0y + w0z * w0z + 1e-12f);
        float c0v = 0.f;
        if (m0 != 0.f && d < 6.f)
            c0v = 0.5f * (__cosf(d * 0.52359877559829887f) + 1.f) / d;
        w0x *= c0v; w0y *= c0v; w0z *= c0v;

        float w1x = pj1v.x - pa.x + o1.x * c00 + o1.y * c10 + o1.z * c20;
        float w1y = pj1v.y - pa.y + o1.x * c01 + o1.y * c11 + o1.z * c21;
        float w1z = pj1v.z - pa.z + o1.x * c02 + o1.y * c12 + o1.z * c22;
        d = sqrtf(w1x * w1x + w1y * w1y + w1z * w1z + 1e-12f);
        float c1v = 0.f;
        if (m1 != 0.f && d < 6.f)
            c1v = 0.5f * (__cosf(d * 0.52359877559829887f) + 1.f) / d;
        w1x *= c1v; w1y *= c1v; w1z *= c1v;

        float w2x = pj2v.x - pi1.x + o2.x * c00 + o2.y * c10 + o2.z * c20;
        float w2y = pj2v.y - pi1.y + o2.x * c01 + o2.y * c11 + o2.z * c21;
        float w2z = pj2v.z - pi1.z + o2.x * c02 + o2.y * c12 + o2.z * c22;
        d = sqrtf(w2x * w2x + w2y * w2y + w2z * w2z + 1e-12f);
        float c2v = 0.f;
        if (m2 != 0.f && d < 6.f)
            c2v = 0.5f * (__cosf(d * 0.52359877559829887f) + 1.f) / d;
        w2x *= c2v; w2y *= c2v; w2z *= c2v;

        // ---- row0: rank + register merge ----
        // rank(m) = #{k: cut_k > cut_m} + #{k<m: cut_k == cut_m}
        float4 a4 = make_float4(0.f, 0.f, 0.f, 0.f);
        float2 a2 = make_float2(0.f, 0.f);
        unsigned long long t = __ballot(c0v != 0.f);
        while (t) {                                  // item m = s (c0 owner)
            const int s = (int)__builtin_ctzll(t); t &= t - 1;
            const float c = __shfl(c0v, s);
            const int rank = __popcll(__ballot(c0v > c))
                           + __popcll(__ballot(c1v > c) & LOWM)
                           + __popcll(__ballot(c0v == c) & ((1ull << s) - 1ull));
            merge3(a4, a2, 3 * rank,
                   __shfl(w0x, s), __shfl(w0y, s), __shfl(w0z, s), lane);
        }
        t = __ballot(c1v != 0.f) & LOWM;
        while (t) {                                  // item m = 64+s (c1 low)
            const int s = (int)__builtin_ctzll(t); t &= t - 1;
            const float c = __shfl(c1v, s);
            const int rank = __popcll(__ballot(c0v > c))
                           + __popcll(__ballot(c1v > c) & LOWM)
                           + __popcll(__ballot(c0v == c))
                           + __popcll(__ballot(c1v == c) & LOWM & ((1ull << s) - 1ull));
            merge3(a4, a2, 3 * rank,
                   __shfl(w1x, s), __shfl(w1y, s), __shfl(w1z, s), lane);
        }
        float* row0 = out + (size_t)q0 * OUT_W;
        ((float4*)row0)[lane] = a4;
        ((float2*)(row0 + 256))[lane] = a2;

        // ---- row1: rank + register merge ----
        float4 b4 = make_float4(0.f, 0.f, 0.f, 0.f);
        float2 b2 = make_float2(0.f, 0.f);
        t = __ballot(c1v != 0.f) & HIGHM;
        while (t) {                                  // item m = s-32 (c1 high)
            const int s = (int)__builtin_ctzll(t); t &= t - 1;
            const float c = __shfl(c1v, s);
            const int rank = __popcll(__ballot(c1v > c) & HIGHM)
                           + __popcll(__ballot(c2v > c))
                           + __popcll(__ballot(c1v == c) & HIGHM & ((1ull << s) - 1ull));
            merge3(b4, b2, 3 * rank,
                   __shfl(w1x, s), __shfl(w1y, s), __shfl(w1z, s), lane);
        }
        t = __ballot(c2v != 0.f);
        while (t) {                                  // item m = 32+s (c2 owner)
            const int s = (int)__builtin_ctzll(t); t &= t - 1;
            const float c = __shfl(c2v, s);
            const int rank = __popcll(__ballot(c1v > c) & HIGHM)
                           + __popcll(__ballot(c2v > c))
                           + __popcll(__ballot(c1v == c) & HIGHM)
                           + __popcll(__ballot(c2v == c) & ((1ull << s) - 1ull));
            merge3(b4, b2, 3 * rank,
                   __shfl(w2x, s), __shfl(w2y, s), __shfl(w2z, s), lane);
        }
        float* row1 = out + (size_t)(q0 + 1) * OUT_W;
        ((float4*)row1)[lane] = b4;
        ((float2*)(row1 + 256))[lane] = b2;
    }
}

extern "C" void kernel_launch(void* const* d_in, const int* in_sizes, int n_in,
                              void* d_out, int out_size, void* d_ws, size_t ws_size,
                              hipStream_t stream) {
    const float* positions = (const float*)d_in[0];
    const float* cell      = (const float*)d_in[1];
    const float* offsets   = (const float*)d_in[2];
    const float* mask      = (const float*)d_in[3];
    const int*   neighbors = (const int*)d_in[4];
    float*       out       = (float*)d_out;

    const int BN = in_sizes[0] / 3;        // B*N = 32768
    const int B  = in_sizes[1] / 9;        // 8
    const int N  = BN / B;                 // 4096

    dim3 block(64 * WPB, 1, 1);            // 512 threads = 8 waves
    dim3 grid(BN / (WPB * 2 * ITERS), 1, 1);   // 512 blocks = 2/CU resident
    deepmd_angular_kernel<<<grid, block, 0, stream>>>(
        positions, cell, offsets, mask, neighbors, out, N);
}